// Round 1
// 80.764 us; speedup vs baseline: 1.1972x; 1.1972x over previous
//
#include <hip/hip_runtime.h>

#define BATCH    1024
#define NUM_VARS 2048
#define LEAVES   (2 * NUM_VARS)              // 4096
#define LEVELS   12
#define WIDTH    4096
#define TOTAL    (LEAVES + LEVELS * WIDTH)   // 53248
#define NWORDS   (TOTAL / 32)                // 1664 bitmask words

#define CAP      2048                        // max active nodes (validated S<=CAP)
#define BSLICE   4                           // batch columns per eval block
#define NEVB     (BATCH / BSLICE)            // 256 eval blocks -> every CU
#define ETHR     1024                        // 16 waves per eval block

#define ROWS     (NUM_VARS + CAP)            // 4096 LDS value rows per column
#define LDPAD    8                           // stride%32==8 -> col groups hit distinct banks
#define LDSTRIDE (ROWS + LDPAD)              // 4104
#define SMEM_BYTES (4 * LDSTRIDE * 4 + CAP * 16 + 64)   // buf + enc + counts ~= 98.5 KB

#define NPREF_X  16                          // x prefetch blocks
#define SETUP_GRID (1 + LEVELS + NPREF_X)    // reach + child prefetch + x prefetch

// Child code packing (unchanged):
//   bits 0..13 : LDS row (0..2047 leaf var v; 2048+slot for node slots)
//   bit 14     : complement (leaf 1-x)
//   bit 20     : op (only in e.x; 0=prod, 1=sum)

// ---------------------------------------------------------------------------
// Setup: block 0 = reachability + record build (serial-critical).
// Blocks 1..12 prefetch child4/op_type into LLC under the marking chain.
// Blocks 13..28 prefetch x into LLC for eval's leaf preload.
// ---------------------------------------------------------------------------
__global__ __launch_bounds__(1024) void setup_kernel(const float* __restrict__ x,
                                                     const int4* __restrict__ child4,
                                                     const int*  __restrict__ op_type,
                                                     int4* __restrict__ enc4,
                                                     int*  __restrict__ counts)
{
    const int tid = threadIdx.x;

    if (blockIdx.x >= 1 && blockIdx.x <= LEVELS) {
        // ---- LLC warm-up for the marking/record loads (concurrent with block 0)
        const int l = blockIdx.x - 1;
        const int4* p = child4 + l * WIDTH;
        const int*  o = op_type + l * WIDTH;
        int acc = 0;
        for (int i = tid; i < WIDTH; i += 1024) {
            const int4 c = p[i];
            acc ^= c.x ^ c.y ^ c.z ^ c.w ^ o[i];
        }
        asm volatile("" :: "v"(acc));        // keep loads live (no DCE), no store
        return;
    }
    if (blockIdx.x > LEVELS) {
        // ---- LLC warm-up for x (eval's leaf preload hits LLC instead of HBM)
        const int b = blockIdx.x - (LEVELS + 1);                // 0..15
        const int per = BATCH * NUM_VARS / 4 / NPREF_X;         // float4s per block
        const float4* px = (const float4*)x + (size_t)b * per;
        float acc = 0.f;
        for (int i = tid; i < per; i += 1024) {
            const float4 v = px[i];
            acc += v.x + v.y + v.z + v.w;
        }
        asm volatile("" :: "v"(acc));
        return;
    }

    // ---- block 0: reachability + record build ----
    __shared__ unsigned int flg[NWORDS];      // 6.5 KB bitmask
    __shared__ int nid[CAP];                  // sorted active node ids
    __shared__ int lvl_cnt[LEVELS], lvl_base[LEVELS];
    __shared__ int total_s;
    const int lane = tid & 63;
    const int wv   = tid >> 6;                // 0..15

    for (int i = tid; i < NWORDS; i += 1024) flg[i] = 0u;
    __syncthreads();
    if (tid == 0) flg[NWORDS - 1] = 0x80000000u;          // root = TOTAL-1
    __syncthreads();

    // backward marking: thread tests its 4 node bits, loads child4 under flag
    for (int l = LEVELS - 1; l >= 0; --l) {
        const int wbase = 128 * (l + 1);
        #pragma unroll
        for (int j = 0; j < 4; ++j) {
            const int k = (tid << 2) | j;     // node index within level
            if ((flg[wbase + (k >> 5)] >> (k & 31)) & 1u) {
                const int4 c = child4[l * WIDTH + k];
                atomicOr(&flg[c.x >> 5], 1u << (c.x & 31));
                atomicOr(&flg[c.y >> 5], 1u << (c.y & 31));
                atomicOr(&flg[c.z >> 5], 1u << (c.z & 31));
                atomicOr(&flg[c.w >> 5], 1u << (c.w & 31));
            }
        }
        __syncthreads();
    }

    // parallel per-level compaction counts (wave wv <-> level wv)
    if (wv < LEVELS) {
        const unsigned int w0 = flg[128 * (wv + 1) + 2 * lane];
        const unsigned int w1 = flg[128 * (wv + 1) + 2 * lane + 1];
        const int pc = __popc(w0) + __popc(w1);
        int scan = pc;
        for (int d = 1; d < 64; d <<= 1) {
            const int up = __shfl_up(scan, d, 64);
            if (lane >= d) scan += up;
        }
        if (lane == 63) lvl_cnt[wv] = scan;
    }
    __syncthreads();
    if (tid == 0) {
        int s = 0;
        for (int l = 0; l < LEVELS; ++l) { lvl_base[l] = s; s += lvl_cnt[l]; }
        total_s = (s < CAP) ? s : CAP;
        for (int l = 0; l < LEVELS; ++l) counts[l] = lvl_cnt[l];
        counts[LEVELS] = total_s;
    }
    __syncthreads();
    if (wv < LEVELS) {                        // write sorted ids
        const unsigned int w0 = flg[128 * (wv + 1) + 2 * lane];
        const unsigned int w1 = flg[128 * (wv + 1) + 2 * lane + 1];
        const int pc = __popc(w0) + __popc(w1);
        int scan = pc;
        for (int d = 1; d < 64; d <<= 1) {
            const int up = __shfl_up(scan, d, 64);
            if (lane >= d) scan += up;
        }
        int base = lvl_base[wv] + scan - pc;
        const int nd0 = LEAVES + wv * WIDTH + 64 * lane;
        unsigned int w = w0;
        while (w) { const int b = __ffs(w) - 1; w &= w - 1;
                    if (base < CAP) nid[base] = nd0 + b;      base++; }
        w = w1;
        while (w) { const int b = __ffs(w) - 1; w &= w - 1;
                    if (base < CAP) nid[base] = nd0 + 32 + b; base++; }
    }
    __syncthreads();

    // one-pass record build; 4-way interleaved branchless binary search
    const int S = total_s;
    for (int slot = tid; slot < S; slot += 1024) {
        const int nd = nid[slot];
        const int4 c = child4[nd - LEAVES];
        const int  o = op_type[nd - LEAVES];
        int lo0 = 0, lo1 = 0, lo2 = 0, lo3 = 0;
        int hi0 = S, hi1 = S, hi2 = S, hi3 = S;
        #pragma unroll
        for (int it = 0; it < 11; ++it) {     // 2^11 >= CAP
            const int m0 = (lo0 + hi0) >> 1, m1 = (lo1 + hi1) >> 1;
            const int m2 = (lo2 + hi2) >> 1, m3 = (lo3 + hi3) >> 1;
            const int n0 = nid[m0], n1 = nid[m1], n2 = nid[m2], n3 = nid[m3];
            if (lo0 < hi0) { if (n0 < c.x) lo0 = m0 + 1; else hi0 = m0; }
            if (lo1 < hi1) { if (n1 < c.y) lo1 = m1 + 1; else hi1 = m1; }
            if (lo2 < hi2) { if (n2 < c.z) lo2 = m2 + 1; else hi2 = m2; }
            if (lo3 < hi3) { if (n3 < c.w) lo3 = m3 + 1; else hi3 = m3; }
        }
        int4 e;
        e.x = (c.x < NUM_VARS) ? c.x : (c.x < LEAVES) ? ((c.x - NUM_VARS) | 0x4000)
                                                      : (NUM_VARS + lo0);
        e.y = (c.y < NUM_VARS) ? c.y : (c.y < LEAVES) ? ((c.y - NUM_VARS) | 0x4000)
                                                      : (NUM_VARS + lo1);
        e.z = (c.z < NUM_VARS) ? c.z : (c.z < LEAVES) ? ((c.z - NUM_VARS) | 0x4000)
                                                      : (NUM_VARS + lo2);
        e.w = (c.w < NUM_VARS) ? c.w : (c.w < LEAVES) ? ((c.w - NUM_VARS) | 0x4000)
                                                      : (NUM_VARS + lo3);
        e.x |= o << 20;
        enc4[slot] = e;
    }
}

// ---------------------------------------------------------------------------
// Evaluation: block b owns batch columns [b*4, b*4+4). The ENTIRE value
// state lives in LDS: buf[c][0..2047] = leaf vars for column c (read
// straight from x, no transpose kernel), buf[c][2048+slot] = node values.
// All gathers are LDS reads; __syncthreads gives level ordering for free.
// 256 blocks -> one per CU, 16 waves each.
// ---------------------------------------------------------------------------
__global__ __launch_bounds__(ETHR) void eval_kernel(const float* __restrict__ x,
                                                    const int4* __restrict__ enc4g,
                                                    const int*  __restrict__ countsg,
                                                    float* __restrict__ out)
{
    extern __shared__ char smem[];
    float* buf      = (float*)smem;                                   // 4*LDSTRIDE f32
    int4*  enc_s    = (int4*)(smem + 4 * LDSTRIDE * sizeof(float));   // CAP int4
    int*   counts_s = (int*)(smem + 4 * LDSTRIDE * sizeof(float) + CAP * sizeof(int4));

    const int tid = threadIdx.x;

    // ---- leaf preload: buf[c][v] = x[(blk*4+c)][v]  (coalesced 256B/wave reads,
    //      consecutive-v LDS writes -> conflict-free)
    {
        const int c  = tid >> 8;              // 0..3
        const int v0 = tid & 255;
        const float* xr = x + (size_t)(blockIdx.x * BSLICE + c) * NUM_VARS;
        float* br = buf + c * LDSTRIDE;
        #pragma unroll
        for (int k = 0; k < NUM_VARS / 256; ++k)
            br[v0 + k * 256] = xr[v0 + k * 256];
    }
    // ---- record + count preload (enc beyond S is never dereferenced)
    #pragma unroll
    for (int i = tid; i < CAP; i += ETHR) enc_s[i] = enc4g[i];
    if (tid < LEVELS) counts_s[tid] = countsg[tid];
    __syncthreads();

    const int col = tid & 3;                  // column within block
    const int nl  = tid >> 2;                 // node lane 0..255
    float* bc = buf + col * LDSTRIDE;

    int sb = 0;
    for (int l = 0; l < LEVELS; ++l) {
        const int n = counts_s[l];
        for (int i = nl; i < n; i += ETHR / BSLICE) {
            const int4 e = enc_s[sb + i];     // 4 lanes same addr -> LDS broadcast
            float v0 = bc[e.x & 0x3FFF];
            float v1 = bc[e.y & 0x3FFF];
            float v2 = bc[e.z & 0x3FFF];
            float v3 = bc[e.w & 0x3FFF];
            v0 = (e.x & 0x4000) ? 1.0f - v0 : v0;
            v1 = (e.y & 0x4000) ? 1.0f - v1 : v1;
            v2 = (e.z & 0x4000) ? 1.0f - v2 : v2;
            v3 = (e.w & 0x4000) ? 1.0f - v3 : v3;
            const float p = ((v0 * v1) * v2) * v3;    // np.prod order
            const float s = ((v0 + v1) + v2) + v3;    // np.sum order
            const float r = (e.x & (1 << 20)) ? s : p;
            bc[NUM_VARS + sb + i] = r;
            if (l == LEVELS - 1 && i == n - 1)
                out[blockIdx.x * BSLICE + col] = r;   // root
        }
        __syncthreads();                      // level boundary (LDS-coherent)
        sb += n;
    }
}

extern "C" void kernel_launch(void* const* d_in, const int* in_sizes, int n_in,
                              void* d_out, int out_size, void* d_ws, size_t ws_size,
                              hipStream_t stream)
{
    const float* x       = (const float*)d_in[0];
    const int4*  child4  = (const int4*)d_in[1];
    const int*   op_type = (const int*)d_in[2];
    float*       out     = (float*)d_out;

    char* w = (char*)d_ws;
    int4* enc4   = (int4*)w;  w += (size_t)CAP * sizeof(int4);   // 32 KB
    int*  counts = (int*)w;   w += 64;

    static bool lds_opted = false;
    if (!lds_opted) {
        hipFuncSetAttribute((const void*)eval_kernel,
                            hipFuncAttributeMaxDynamicSharedMemorySize, SMEM_BYTES);
        lds_opted = true;
    }

    setup_kernel<<<SETUP_GRID, 1024, 0, stream>>>(x, child4, op_type, enc4, counts);
    eval_kernel<<<NEVB, ETHR, SMEM_BYTES, stream>>>(x, enc4, counts, out);
}

// Round 2
// 79.324 us; speedup vs baseline: 1.2189x; 1.0182x over previous
//
#include <hip/hip_runtime.h>

#define BATCH    1024
#define NUM_VARS 2048
#define LEAVES   (2 * NUM_VARS)              // 4096
#define LEVELS   12
#define WIDTH    4096
#define TOTAL    (LEAVES + LEVELS * WIDTH)   // 53248
#define NWORDS   (TOTAL / 32)                // 1664 bitmask words

#define CAP      2048                        // max active nodes (validated S<=CAP)
#define BSLICE   4                           // batch columns per eval block
#define NEVB     (BATCH / BSLICE)            // 256 eval blocks -> every CU
#define ETHR     1024                        // 16 waves per eval block

#define ROWS     (NUM_VARS + CAP)            // 4096 LDS value rows per column
#define LDPAD    8                           // stride%32==8 -> col groups hit distinct banks
#define LDSTRIDE (ROWS + LDPAD)              // 4104
#define SMEM_BYTES (4 * LDSTRIDE * 4 + CAP * 16 + 64)   // buf + enc + counts ~= 98.5 KB

#define PREF_SPLIT 8                         // prefetch blocks per level (wide + shallow)
#define NPREF      (LEVELS * PREF_SPLIT)     // 96
#define SETUP_GRID (1 + NPREF)

// Child code packing:
//   bits 0..13 : LDS row (0..2047 leaf var v; 2048+slot for node slots)
//   bit 14     : complement (leaf 1-x)
//   bit 20     : op (only in e.x; 0=prod, 1=sum)

// ---------------------------------------------------------------------------
// Setup: block 0 = reachability + record build (serial-critical).
// Blocks 1..96 prefetch child4/op_type into LLC under the marking chain —
// each reads only 8 KB + 2 KB so their duration (~1 us, latency-bound)
// never exceeds block 0's chain. NO x prefetch: eval's 256 blocks read x
// at full machine BW themselves (r1 lesson: 16-block prefetch of 8 MB was
// a ~20 us serial prefix on the setup dispatch).
// ---------------------------------------------------------------------------
__global__ __launch_bounds__(1024) void setup_kernel(const int4* __restrict__ child4,
                                                     const int*  __restrict__ op_type,
                                                     int4* __restrict__ enc4,
                                                     int*  __restrict__ counts)
{
    const int tid = threadIdx.x;

    if (blockIdx.x >= 1) {
        // ---- LLC warm-up for the marking/record loads (concurrent with block 0)
        const int seg   = blockIdx.x - 1;                 // 0..95
        const int l     = seg / PREF_SPLIT;
        const int part  = seg % PREF_SPLIT;
        const int cnt   = WIDTH / PREF_SPLIT;             // 512 nodes
        const int base  = l * WIDTH + part * cnt;
        int acc = 0;
        for (int i = tid; i < cnt; i += 1024) {
            const int4 c = child4[base + i];
            acc ^= c.x ^ c.y ^ c.z ^ c.w ^ op_type[base + i];
        }
        asm volatile("" :: "v"(acc));        // keep loads live (no DCE), no store
        return;
    }

    // ---- block 0: reachability + record build ----
    __shared__ unsigned int flg[NWORDS];      // 6.5 KB bitmask
    __shared__ int nid[CAP];                  // sorted active node ids
    __shared__ int lvl_cnt[LEVELS], lvl_base[LEVELS];
    __shared__ int total_s;
    const int lane = tid & 63;
    const int wv   = tid >> 6;                // 0..15

    for (int i = tid; i < NWORDS; i += 1024) flg[i] = 0u;
    __syncthreads();
    if (tid == 0) flg[NWORDS - 1] = 0x80000000u;          // root = TOTAL-1
    __syncthreads();

    // backward marking: thread tests its 4 node bits, loads child4 under flag
    for (int l = LEVELS - 1; l >= 0; --l) {
        const int wbase = 128 * (l + 1);
        #pragma unroll
        for (int j = 0; j < 4; ++j) {
            const int k = (tid << 2) | j;     // node index within level
            if ((flg[wbase + (k >> 5)] >> (k & 31)) & 1u) {
                const int4 c = child4[l * WIDTH + k];
                atomicOr(&flg[c.x >> 5], 1u << (c.x & 31));
                atomicOr(&flg[c.y >> 5], 1u << (c.y & 31));
                atomicOr(&flg[c.z >> 5], 1u << (c.z & 31));
                atomicOr(&flg[c.w >> 5], 1u << (c.w & 31));
            }
        }
        __syncthreads();
    }

    // parallel per-level compaction counts (wave wv <-> level wv)
    if (wv < LEVELS) {
        const unsigned int w0 = flg[128 * (wv + 1) + 2 * lane];
        const unsigned int w1 = flg[128 * (wv + 1) + 2 * lane + 1];
        const int pc = __popc(w0) + __popc(w1);
        int scan = pc;
        for (int d = 1; d < 64; d <<= 1) {
            const int up = __shfl_up(scan, d, 64);
            if (lane >= d) scan += up;
        }
        if (lane == 63) lvl_cnt[wv] = scan;
    }
    __syncthreads();
    if (tid == 0) {
        int s = 0;
        for (int l = 0; l < LEVELS; ++l) { lvl_base[l] = s; s += lvl_cnt[l]; }
        total_s = (s < CAP) ? s : CAP;
        for (int l = 0; l < LEVELS; ++l) counts[l] = lvl_cnt[l];
        counts[LEVELS] = total_s;
    }
    __syncthreads();
    if (wv < LEVELS) {                        // write sorted ids
        const unsigned int w0 = flg[128 * (wv + 1) + 2 * lane];
        const unsigned int w1 = flg[128 * (wv + 1) + 2 * lane + 1];
        const int pc = __popc(w0) + __popc(w1);
        int scan = pc;
        for (int d = 1; d < 64; d <<= 1) {
            const int up = __shfl_up(scan, d, 64);
            if (lane >= d) scan += up;
        }
        int base = lvl_base[wv] + scan - pc;
        const int nd0 = LEAVES + wv * WIDTH + 64 * lane;
        unsigned int w = w0;
        while (w) { const int b = __ffs(w) - 1; w &= w - 1;
                    if (base < CAP) nid[base] = nd0 + b;      base++; }
        w = w1;
        while (w) { const int b = __ffs(w) - 1; w &= w - 1;
                    if (base < CAP) nid[base] = nd0 + 32 + b; base++; }
    }
    __syncthreads();

    // one-pass record build; 4-way interleaved branchless binary search
    const int S = total_s;
    for (int slot = tid; slot < S; slot += 1024) {
        const int nd = nid[slot];
        const int4 c = child4[nd - LEAVES];
        const int  o = op_type[nd - LEAVES];
        int lo0 = 0, lo1 = 0, lo2 = 0, lo3 = 0;
        int hi0 = S, hi1 = S, hi2 = S, hi3 = S;
        #pragma unroll
        for (int it = 0; it < 11; ++it) {     // 2^11 >= CAP
            const int m0 = (lo0 + hi0) >> 1, m1 = (lo1 + hi1) >> 1;
            const int m2 = (lo2 + hi2) >> 1, m3 = (lo3 + hi3) >> 1;
            const int n0 = nid[m0], n1 = nid[m1], n2 = nid[m2], n3 = nid[m3];
            if (lo0 < hi0) { if (n0 < c.x) lo0 = m0 + 1; else hi0 = m0; }
            if (lo1 < hi1) { if (n1 < c.y) lo1 = m1 + 1; else hi1 = m1; }
            if (lo2 < hi2) { if (n2 < c.z) lo2 = m2 + 1; else hi2 = m2; }
            if (lo3 < hi3) { if (n3 < c.w) lo3 = m3 + 1; else hi3 = m3; }
        }
        int4 e;
        e.x = (c.x < NUM_VARS) ? c.x : (c.x < LEAVES) ? ((c.x - NUM_VARS) | 0x4000)
                                                      : (NUM_VARS + lo0);
        e.y = (c.y < NUM_VARS) ? c.y : (c.y < LEAVES) ? ((c.y - NUM_VARS) | 0x4000)
                                                      : (NUM_VARS + lo1);
        e.z = (c.z < NUM_VARS) ? c.z : (c.z < LEAVES) ? ((c.z - NUM_VARS) | 0x4000)
                                                      : (NUM_VARS + lo2);
        e.w = (c.w < NUM_VARS) ? c.w : (c.w < LEAVES) ? ((c.w - NUM_VARS) | 0x4000)
                                                      : (NUM_VARS + lo3);
        e.x |= o << 20;
        enc4[slot] = e;
    }
}

// ---------------------------------------------------------------------------
// Evaluation: block b owns batch columns [b*4, b*4+4). The ENTIRE value
// state lives in LDS: buf[c][0..2047] = leaf vars for column c (read
// straight from x), buf[c][2048+slot] = node values. All gathers are LDS
// reads; __syncthreads gives level ordering for free. 256 blocks -> one
// per CU, 16 waves each.
// ---------------------------------------------------------------------------
__global__ __launch_bounds__(ETHR) void eval_kernel(const float* __restrict__ x,
                                                    const int4* __restrict__ enc4g,
                                                    const int*  __restrict__ countsg,
                                                    float* __restrict__ out)
{
    extern __shared__ char smem[];
    float* buf      = (float*)smem;                                   // 4*LDSTRIDE f32
    int4*  enc_s    = (int4*)(smem + 4 * LDSTRIDE * sizeof(float));   // CAP int4
    int*   counts_s = (int*)(smem + 4 * LDSTRIDE * sizeof(float) + CAP * sizeof(int4));

    const int tid = threadIdx.x;

    // ---- leaf preload: buf[c][v] = x[(blk*4+c)][v]  (coalesced 256B/wave reads,
    //      consecutive-v LDS writes -> conflict-free)
    {
        const int c  = tid >> 8;              // 0..3
        const int v0 = tid & 255;
        const float* xr = x + (size_t)(blockIdx.x * BSLICE + c) * NUM_VARS;
        float* br = buf + c * LDSTRIDE;
        #pragma unroll
        for (int k = 0; k < NUM_VARS / 256; ++k)
            br[v0 + k * 256] = xr[v0 + k * 256];
    }
    // ---- record + count preload (enc beyond S is never dereferenced)
    #pragma unroll
    for (int i = tid; i < CAP; i += ETHR) enc_s[i] = enc4g[i];
    if (tid < LEVELS) counts_s[tid] = countsg[tid];
    __syncthreads();

    const int col = tid & 3;                  // column within block
    const int nl  = tid >> 2;                 // node lane 0..255
    float* bc = buf + col * LDSTRIDE;

    int sb = 0;
    for (int l = 0; l < LEVELS; ++l) {
        const int n = counts_s[l];
        for (int i = nl; i < n; i += ETHR / BSLICE) {
            const int4 e = enc_s[sb + i];     // 4 lanes same addr -> LDS broadcast
            float v0 = bc[e.x & 0x3FFF];
            float v1 = bc[e.y & 0x3FFF];
            float v2 = bc[e.z & 0x3FFF];
            float v3 = bc[e.w & 0x3FFF];
            v0 = (e.x & 0x4000) ? 1.0f - v0 : v0;
            v1 = (e.y & 0x4000) ? 1.0f - v1 : v1;
            v2 = (e.z & 0x4000) ? 1.0f - v2 : v2;
            v3 = (e.w & 0x4000) ? 1.0f - v3 : v3;
            const float p = ((v0 * v1) * v2) * v3;    // np.prod order
            const float s = ((v0 + v1) + v2) + v3;    // np.sum order
            const float r = (e.x & (1 << 20)) ? s : p;
            bc[NUM_VARS + sb + i] = r;
            if (l == LEVELS - 1 && i == n - 1)
                out[blockIdx.x * BSLICE + col] = r;   // root
        }
        __syncthreads();                      // level boundary (LDS-coherent)
        sb += n;
    }
}

extern "C" void kernel_launch(void* const* d_in, const int* in_sizes, int n_in,
                              void* d_out, int out_size, void* d_ws, size_t ws_size,
                              hipStream_t stream)
{
    const float* x       = (const float*)d_in[0];
    const int4*  child4  = (const int4*)d_in[1];
    const int*   op_type = (const int*)d_in[2];
    float*       out     = (float*)d_out;

    char* w = (char*)d_ws;
    int4* enc4   = (int4*)w;  w += (size_t)CAP * sizeof(int4);   // 32 KB
    int*  counts = (int*)w;   w += 64;

    static bool lds_opted = false;
    if (!lds_opted) {
        hipFuncSetAttribute((const void*)eval_kernel,
                            hipFuncAttributeMaxDynamicSharedMemorySize, SMEM_BYTES);
        lds_opted = true;
    }

    setup_kernel<<<SETUP_GRID, 1024, 0, stream>>>(child4, op_type, enc4, counts);
    eval_kernel<<<NEVB, ETHR, SMEM_BYTES, stream>>>(x, enc4, counts, out);
}